// Round 4
// baseline (584.758 us; speedup 1.0000x reference)
//
#include <hip/hip_runtime.h>

typedef __attribute__((ext_vector_type(8))) short bf16x8;
typedef __attribute__((ext_vector_type(4))) float f32x4;

// ---------- helpers ----------
__device__ __forceinline__ unsigned short bf16_rne(float x){
  unsigned int u = __float_as_uint(x);
  unsigned int r = (u + 0x7FFFu + ((u >> 16) & 1u)) >> 16;
  return (unsigned short)r;
}
__device__ __forceinline__ float bf16_tof(unsigned short h){
  return __uint_as_float(((unsigned int)h) << 16);
}
__device__ __forceinline__ void split2(float x, unsigned short &hi, unsigned short &lo){
  hi = bf16_rne(x);
  lo = bf16_rne(x - bf16_tof(hi));
}
__device__ __forceinline__ void gload_lds16(const void* g, void* l){
  __builtin_amdgcn_global_load_lds((const __attribute__((address_space(1))) void*)g,
                                   (__attribute__((address_space(3))) void*)l, 16, 0, 0);
}
#define VM(N)  asm volatile("s_waitcnt vmcnt(" #N ")" ::: "memory")
#define LGKM0()  do { asm volatile("s_waitcnt lgkmcnt(0)" ::: "memory"); \
                      __builtin_amdgcn_sched_barrier(0); } while(0)
#define BAR()  do { __builtin_amdgcn_s_barrier(); \
                    __builtin_amdgcn_sched_barrier(0); } while(0)

// K-index remap for the 3-term split expressed as a K=3072 concat GEMM.
// MAP 0: identity. MAP 1: blocks [hi|lo|hi]. MAP 2: blocks [hi|hi|lo].
template<int MAP>
__device__ __forceinline__ int kmap(int k){
  if (MAP == 1) return (k < 2048) ? k : (k - 2048);
  if (MAP == 2) return (k < 1024) ? k : (k - 1024);
  return k;
}

// ============================================================================
// Phased 256x256 GEMM, BK=64, 512 threads (8 waves 2x4), 2 LDS slots x 64KB.
// 4 phases per K-tile; per phase: stage 1 quarter (2 gloads) -> vmcnt(6) ->
// barrier -> ds_read (4 or 8) -> lgkmcnt(0) -> 16 MFMA (setprio-wrapped).
// Slot layout: [A k0 16K | A k1 16K | B k0 16K | B k1 16K], each 16K region
// in the R2-verified XOR-swizzled order (0 bank conflicts measured).
// Stream order per tile: Q0=A.k0, Q1=B.k0, Q2=B.k1, Q3=A.k1 (stage of tile
// t+1 spread over the 4 phases of tile t).
// EPI 0: split hi/lo write (y). EPI 1: bf16(acc+bias[col])^T write (featsT).
// ============================================================================
template<int MAPA, int MAPB, int NK, int EPI>
__global__ __launch_bounds__(512, 2) void k_gemm256(
    const unsigned short* __restrict__ A, const unsigned short* __restrict__ B,
    unsigned short* __restrict__ outp, const float* __restrict__ bias)
{
  __shared__ __align__(16) unsigned short lds_u[65536];   // 128 KiB
  char* ldsb = (char*)lds_u;

  int bid = blockIdx.x;                 // XCD-aware swizzle (grid 512 % 8 == 0)
  bid = (bid & 7) * 64 + (bid >> 3);
  const int bm = bid >> 2, bn = bid & 3;

  const int tid  = threadIdx.x;
  const int w    = tid >> 6;
  const int lane = tid & 63;
  const int wm   = w >> 2;              // 0..1
  const int wn   = w & 3;               // 0..3
  const int l15  = lane & 15;
  const int lg   = lane >> 4;

  // staging source map (inverse swizzle), 2 chunks per 16K region
  int srow[2], slg[2];
#pragma unroll
  for (int j = 0; j < 2; j++){
    int o16 = j * 512 + tid;
    int p = o16 >> 3, s = o16 & 7;
    int q = s ^ (p & 7);
    srow[j] = 2 * p + (q >> 2);
    slg[j]  = q & 3;
  }
  const unsigned short* aS0 = A + (size_t)(bm * 256 + srow[0]) * 2048 + slg[0] * 8;
  const unsigned short* aS1 = A + (size_t)(bm * 256 + srow[1]) * 2048 + slg[1] * 8;
  const unsigned short* bS0 = B + (size_t)(bn * 256 + srow[0]) * 2048 + slg[0] * 8;
  const unsigned short* bS1 = B + (size_t)(bn * 256 + srow[1]) * 2048 + slg[1] * 8;

  // swizzled ds_read lane offset
  const int sA   = (((l15 & 1) << 2) | lg) ^ ((l15 >> 1) & 7);
  const int rps  = (l15 >> 1) * 128 + sA * 16;

  f32x4 acc[8][4];
  f32x4 zero = {0.f, 0.f, 0.f, 0.f};
#pragma unroll
  for (int m = 0; m < 8; m++)
#pragma unroll
    for (int n = 0; n < 4; n++) acc[m][n] = zero;

  auto STAGE_Q = [&](int t, int q){
    char* slot = ldsb + (size_t)(t & 1) * 65536;
    const int kbA = kmap<MAPA>(t * 64);
    const int kbB = kmap<MAPB>(t * 64);
    if (q == 0){                        // A ksub0
      gload_lds16(aS0 + kbA,      slot +         w * 1024);
      gload_lds16(aS1 + kbA,      slot +  8192 + w * 1024);
    } else if (q == 1){                 // B ksub0
      gload_lds16(bS0 + kbB,      slot + 32768 + w * 1024);
      gload_lds16(bS1 + kbB,      slot + 40960 + w * 1024);
    } else if (q == 2){                 // B ksub1
      gload_lds16(bS0 + kbB + 32, slot + 49152 + w * 1024);
      gload_lds16(bS1 + kbB + 32, slot + 57344 + w * 1024);
    } else {                            // A ksub1
      gload_lds16(aS0 + kbA + 32, slot + 16384 + w * 1024);
      gload_lds16(aS1 + kbA + 32, slot + 24576 + w * 1024);
    }
  };

  // prologue: full tile 0 in stream order
  STAGE_Q(0, 0); STAGE_Q(0, 1); STAGE_Q(0, 2); STAGE_Q(0, 3);

#pragma unroll 1
  for (int t = 0; t < NK; t++){
    const char* sb = ldsb + (size_t)(t & 1) * 65536;
    const bool pre = (t + 1 < NK);
    bf16x8 aF[4], bF[4], aG[4], bF2[4], aF2[4], aG2[4];

    // ---- P0: A[m0-3,k0] x B[n,k0] ----
    if (pre) STAGE_Q(t + 1, 0);
    if (pre) { VM(6); } else { VM(4); }
    BAR();
#pragma unroll
    for (int m = 0; m < 4; m++) aF[m] = *(const bf16x8*)(sb + wm * 8192 + m * 1024 + rps);
#pragma unroll
    for (int n = 0; n < 4; n++) bF[n] = *(const bf16x8*)(sb + 32768 + wn * 4096 + n * 1024 + rps);
    LGKM0();
    __builtin_amdgcn_s_setprio(1);
#pragma unroll
    for (int m = 0; m < 4; m++)
#pragma unroll
      for (int n = 0; n < 4; n++)
        acc[m][n] = __builtin_amdgcn_mfma_f32_16x16x32_bf16(aF[m], bF[n], acc[m][n], 0, 0, 0);
    __builtin_amdgcn_s_setprio(0);

    // ---- P1: A[m4-7,k0] x B[n,k0]; read B k1 ----
    if (pre) STAGE_Q(t + 1, 1);
    if (pre) { VM(6); } else { VM(2); }
    BAR();
#pragma unroll
    for (int m = 0; m < 4; m++) aG[m] = *(const bf16x8*)(sb + wm * 8192 + (m + 4) * 1024 + rps);
#pragma unroll
    for (int n = 0; n < 4; n++) bF2[n] = *(const bf16x8*)(sb + 49152 + wn * 4096 + n * 1024 + rps);
    LGKM0();
    __builtin_amdgcn_s_setprio(1);
#pragma unroll
    for (int m = 0; m < 4; m++)
#pragma unroll
      for (int n = 0; n < 4; n++)
        acc[m + 4][n] = __builtin_amdgcn_mfma_f32_16x16x32_bf16(aG[m], bF[n], acc[m + 4][n], 0, 0, 0);
    __builtin_amdgcn_s_setprio(0);

    // ---- P2: A[m0-3,k1] x B[n,k1] ----
    if (pre) STAGE_Q(t + 1, 2);
    if (pre) { VM(6); } else { VM(0); }
    BAR();
#pragma unroll
    for (int m = 0; m < 4; m++) aF2[m] = *(const bf16x8*)(sb + 16384 + wm * 8192 + m * 1024 + rps);
    LGKM0();
    __builtin_amdgcn_s_setprio(1);
#pragma unroll
    for (int m = 0; m < 4; m++)
#pragma unroll
      for (int n = 0; n < 4; n++)
        acc[m][n] = __builtin_amdgcn_mfma_f32_16x16x32_bf16(aF2[m], bF2[n], acc[m][n], 0, 0, 0);
    __builtin_amdgcn_s_setprio(0);

    // ---- P3: A[m4-7,k1] x B[n,k1] ----
    if (pre) STAGE_Q(t + 1, 3);
    BAR();
#pragma unroll
    for (int m = 0; m < 4; m++) aG2[m] = *(const bf16x8*)(sb + 16384 + wm * 8192 + (m + 4) * 1024 + rps);
    LGKM0();
    __builtin_amdgcn_s_setprio(1);
#pragma unroll
    for (int m = 0; m < 4; m++)
#pragma unroll
      for (int n = 0; n < 4; n++)
        acc[m + 4][n] = __builtin_amdgcn_mfma_f32_16x16x32_bf16(aG2[m], bF2[n], acc[m + 4][n], 0, 0, 0);
    __builtin_amdgcn_s_setprio(0);
  }

#pragma unroll
  for (int m = 0; m < 8; m++)
#pragma unroll
    for (int n = 0; n < 4; n++){
      const int col  = bn * 256 + wn * 64 + n * 16 + l15;
      const int row0 = bm * 256 + wm * 128 + m * 16 + lg * 4;
      if (EPI == 0){
#pragma unroll
        for (int q = 0; q < 4; q++){
          unsigned short hi, lo; split2(acc[m][n][q], hi, lo);
          const size_t base = (size_t)(row0 + q) * 2048;
          outp[base + col] = hi;
          outp[base + 1024 + col] = lo;
        }
      } else {
        const float bgv = bias[col];
        ushort4 h4;
        h4.x = bf16_rne(acc[m][n][0] + bgv); h4.y = bf16_rne(acc[m][n][1] + bgv);
        h4.z = bf16_rne(acc[m][n][2] + bgv); h4.w = bf16_rne(acc[m][n][3] + bgv);
        *(ushort4*)(outp + (size_t)col * 32768 + row0) = h4;
      }
    }
}

// ============================================================================
// Phased per-frame scores + fused softmax: 2 frames/block, 512 threads,
// BK=64, 2 LDS slots x 64KB (regions: Yf0|Xf0|Yf1|Xf1, each 16K = 2 ksubs).
// 2 phases per K-tile: stage half (4 gloads) -> vmcnt(8) -> barrier ->
// 8 ds_read -> lgkm0 -> 16 MFMA. A=Y2 (MAP2), B=X2 (MAP1), K=3072.
// ============================================================================
__global__ __launch_bounds__(512, 2) void k_scores2(
    const unsigned short* __restrict__ Y2, const unsigned short* __restrict__ X2,
    const float* __restrict__ v, unsigned short* __restrict__ wout)
{
  __shared__ __align__(16) unsigned short lds_u[65536];   // 128 KiB
  char* ldsb = (char*)lds_u;

  const int f0 = blockIdx.x * 2;
  const int tid  = threadIdx.x;
  const int w    = tid >> 6;
  const int lane = tid & 63;
  const int fh   = w >> 2;
  const int wq   = w & 3;
  const int wm   = wq >> 1, wn = wq & 1;
  const int l15  = lane & 15;
  const int lg   = lane >> 4;

  // staging chunk map (128-row regions: p in [0,64))
  const int pS = tid >> 3, sS = tid & 7;
  const int qS = sS ^ (pS & 7);
  const int srowS = 2 * pS + (qS >> 2);
  const int slgS  = qS & 3;
  const unsigned short* yS0 = Y2 + (size_t)((f0    ) * 128 + srowS) * 2048 + slgS * 8;
  const unsigned short* xS0 = X2 + (size_t)((f0    ) * 128 + srowS) * 2048 + slgS * 8;
  const unsigned short* yS1 = Y2 + (size_t)((f0 + 1) * 128 + srowS) * 2048 + slgS * 8;
  const unsigned short* xS1 = X2 + (size_t)((f0 + 1) * 128 + srowS) * 2048 + slgS * 8;

  const int sA  = (((l15 & 1) << 2) | lg) ^ ((l15 >> 1) & 7);
  const int rps = (l15 >> 1) * 128 + sA * 16;

  f32x4 acc[4][4];
  f32x4 zero = {0.f, 0.f, 0.f, 0.f};
#pragma unroll
  for (int m = 0; m < 4; m++)
#pragma unroll
    for (int n = 0; n < 4; n++) acc[m][n] = zero;

  auto STAGE_H = [&](int t, int ks){
    char* slot = ldsb + (size_t)(t & 1) * 65536;
    const int kY = kmap<2>(t * 64) + ks * 32;
    const int kX = kmap<1>(t * 64) + ks * 32;
    gload_lds16(yS0 + kY, slot +         ks * 8192 + w * 1024);
    gload_lds16(xS0 + kX, slot + 16384 + ks * 8192 + w * 1024);
    gload_lds16(yS1 + kY, slot + 32768 + ks * 8192 + w * 1024);
    gload_lds16(xS1 + kX, slot + 49152 + ks * 8192 + w * 1024);
  };

  const int NK = 48;
  STAGE_H(0, 0); STAGE_H(0, 1);

#pragma unroll 1
  for (int t = 0; t < NK; t++){
    const char* sb = ldsb + (size_t)(t & 1) * 65536 + fh * 32768;
    const bool pre = (t + 1 < NK);
    bf16x8 aF[4], bF[4], aF2[4], bF2[4];

    // ---- P0: k0 ----
    if (pre) STAGE_H(t + 1, 0);
    if (pre) { VM(8); } else { VM(4); }
    BAR();
#pragma unroll
    for (int m = 0; m < 4; m++) aF[m] = *(const bf16x8*)(sb + wm * 4096 + m * 1024 + rps);
#pragma unroll
    for (int n = 0; n < 4; n++) bF[n] = *(const bf16x8*)(sb + 16384 + wn * 4096 + n * 1024 + rps);
    LGKM0();
    __builtin_amdgcn_s_setprio(1);
#pragma unroll
    for (int m = 0; m < 4; m++)
#pragma unroll
      for (int n = 0; n < 4; n++)
        acc[m][n] = __builtin_amdgcn_mfma_f32_16x16x32_bf16(aF[m], bF[n], acc[m][n], 0, 0, 0);
    __builtin_amdgcn_s_setprio(0);

    // ---- P1: k1 ----
    if (pre) STAGE_H(t + 1, 1);
    if (pre) { VM(8); } else { VM(0); }
    BAR();
#pragma unroll
    for (int m = 0; m < 4; m++) aF2[m] = *(const bf16x8*)(sb + 8192 + wm * 4096 + m * 1024 + rps);
#pragma unroll
    for (int n = 0; n < 4; n++) bF2[n] = *(const bf16x8*)(sb + 24576 + wn * 4096 + n * 1024 + rps);
    LGKM0();
    __builtin_amdgcn_s_setprio(1);
#pragma unroll
    for (int m = 0; m < 4; m++)
#pragma unroll
      for (int n = 0; n < 4; n++)
        acc[m][n] = __builtin_amdgcn_mfma_f32_16x16x32_bf16(aF2[m], bF2[n], acc[m][n], 0, 0, 0);
    __builtin_amdgcn_s_setprio(0);
  }

  // ---- fused softmax: acc -> LDS fp32 (rotation swizzle), reduce, bf16 out ----
  BAR();
  float* sf = (float*)ldsb;                     // 2 x 64KB fp32 frames
#pragma unroll
  for (int m = 0; m < 4; m++)
#pragma unroll
    for (int n = 0; n < 4; n++){
      const int col = wn * 64 + n * 16 + l15;
#pragma unroll
      for (int q = 0; q < 4; q++){
        const int row = wm * 64 + m * 16 + lg * 4 + q;
        sf[fh * 16384 + row * 128 + ((col + (row & 31) * 4) & 127)] = acc[m][n][q];
      }
    }
  __syncthreads();
#pragma unroll 1
  for (int i = 0; i < 32; i++){
    const int rr  = w * 32 + i;                 // 0..255
    const int fhh = rr >> 7, row = rr & 127;
    const float* rp = sf + fhh * 16384 + row * 128;
    const float* vr = v + (size_t)(f0 + fhh) * 128;
    const int rot = (row & 31) * 4;
    float a = rp[(lane + rot) & 127]      + vr[lane];
    float b = rp[(lane + 64 + rot) & 127] + vr[lane + 64];
    float mx = fmaxf(a, b);
    for (int o = 32; o; o >>= 1) mx = fmaxf(mx, __shfl_xor(mx, o));
    float ea = __expf(a - mx), eb = __expf(b - mx);
    float s = ea + eb;
    for (int o = 32; o; o >>= 1) s += __shfl_xor(s, o);
    const float inv = 1.0f / s;
    unsigned short* wrow = wout + ((size_t)(f0 + fhh) * 128 + row) * 128;
    wrow[lane]      = bf16_rne(ea * inv);
    wrow[lane + 64] = bf16_rne(eb * inv);
  }
}

// ============================================================================
// m97-style core for the small GEMMs (mt: 64 blocks; out: K=128).
// ============================================================================
template<int MAPA, int MAPB>
__device__ __forceinline__ void gemm_core(const unsigned short* __restrict__ A, int lda,
                                          const unsigned short* __restrict__ B, int ldb,
                                          int Kv,
                                          unsigned short* lsA, unsigned short* lsB,
                                          f32x4 acc[4][4])
{
  const int tid  = threadIdx.x;
  const int lane = tid & 63;
  const int w    = tid >> 6;
  const int wr   = (w >> 1) * 64;
  const int wc   = (w & 1) * 64;
  const int l15  = lane & 15;
  const int lg   = lane >> 4;

  f32x4 zero = {0.f, 0.f, 0.f, 0.f};
#pragma unroll
  for (int m = 0; m < 4; m++)
#pragma unroll
    for (int n = 0; n < 4; n++)
      acc[m][n] = zero;

  const int srow = tid >> 3;
  const int skk  = (tid & 7) << 3;

  for (int kt = 0; kt < Kv; kt += 64){
    const int ka = kmap<MAPA>(kt) + skk;
    const int kb = kmap<MAPB>(kt) + skk;
    __syncthreads();
#pragma unroll
    for (int i = 0; i < 4; i++){
      const int row = i * 32 + srow;
      gload_lds16(A + (size_t)row * lda + ka, lsA + i * 2048 + w * 512);
      gload_lds16(B + (size_t)row * ldb + kb, lsB + i * 2048 + w * 512);
    }
    __syncthreads();
#pragma unroll
    for (int s2 = 0; s2 < 2; s2++){
      bf16x8 af[4], bfr[4];
#pragma unroll
      for (int m = 0; m < 4; m++)
        af[m] = *(const bf16x8*)(lsA + (wr + m * 16 + l15) * 64 + s2 * 32 + lg * 8);
#pragma unroll
      for (int n = 0; n < 4; n++)
        bfr[n] = *(const bf16x8*)(lsB + (wc + n * 16 + l15) * 64 + s2 * 32 + lg * 8);
#pragma unroll
      for (int m = 0; m < 4; m++)
#pragma unroll
        for (int n = 0; n < 4; n++)
          acc[m][n] = __builtin_amdgcn_mfma_f32_16x16x32_bf16(af[m], bfr[n], acc[m][n], 0, 0, 0);
    }
  }
}

// ---------- small prep kernels ----------
__global__ __launch_bounds__(256) void k_split(const float* __restrict__ src,
                                               unsigned short* __restrict__ dst){
  const int row = blockIdx.x;
  const int c = threadIdx.x * 4;
  float4 val = *(const float4*)(src + (size_t)row * 1024 + c);
  ushort4 h, l;
  split2(val.x, h.x, l.x); split2(val.y, h.y, l.y);
  split2(val.z, h.z, l.z); split2(val.w, h.w, l.w);
  *(ushort4*)(dst + (size_t)row * 2048 + c) = h;
  *(ushort4*)(dst + (size_t)row * 2048 + 1024 + c) = l;
}

__global__ __launch_bounds__(256) void k_splitT(const float* __restrict__ src,
                                                unsigned short* __restrict__ dstT){
  const int row = blockIdx.x;
  const int c0 = threadIdx.x * 4;
  float4 val = *(const float4*)(src + (size_t)row * 1024 + c0);
  float vv[4] = {val.x, val.y, val.z, val.w};
#pragma unroll
  for (int i = 0; i < 4; i++){
    unsigned short h, l; split2(vv[i], h, l);
    dstT[(size_t)(c0 + i) * 2048 + row] = h;
    dstT[(size_t)(c0 + i) * 2048 + 1024 + row] = l;
  }
}

__global__ __launch_bounds__(256) void k_wv(const float* __restrict__ Wb,
                                            const float* __restrict__ ba,
                                            float* __restrict__ wv){
  const int row = blockIdx.x * 4 + (threadIdx.x >> 6);
  const int lane = threadIdx.x & 63;
  float s = 0.f;
#pragma unroll
  for (int j = 0; j < 4; j++){
    const int c = lane * 4 + j * 256;
    float4 wb = *(const float4*)(Wb + (size_t)row * 1024 + c);
    float4 bb = *(const float4*)(ba + c);
    s += wb.x * bb.x + wb.y * bb.y + wb.z * bb.z + wb.w * bb.w;
  }
  for (int o = 32; o; o >>= 1) s += __shfl_xor(s, o);
  if (lane == 0) wv[row] = s;
}

// x split + v dot: one wave per row, 4 rows/block, grid-stride. grid 2048.
__global__ __launch_bounds__(256) void k_split_x(const float* __restrict__ x,
                                                 unsigned short* __restrict__ x2,
                                                 const float* __restrict__ wv,
                                                 float* __restrict__ v){
  const int w = threadIdx.x >> 6, lane = threadIdx.x & 63;
#pragma unroll
  for (int it = 0; it < 4; it++){
    const int row = blockIdx.x * 4 + w + it * 8192;
    float s = 0.f;
#pragma unroll
    for (int j = 0; j < 4; j++){
      const int c = lane * 4 + j * 256;
      float4 val = *(const float4*)(x + (size_t)row * 1024 + c);
      float4 wvv = *(const float4*)(wv + c);
      ushort4 h, l;
      split2(val.x, h.x, l.x); split2(val.y, h.y, l.y);
      split2(val.z, h.z, l.z); split2(val.w, h.w, l.w);
      *(ushort4*)(x2 + (size_t)row * 2048 + c) = h;
      *(ushort4*)(x2 + (size_t)row * 2048 + 1024 + c) = l;
      s += val.x * wvv.x + val.y * wvv.y + val.z * wvv.z + val.w * wvv.w;
    }
    for (int o = 32; o; o >>= 1) s += __shfl_xor(s, o);
    if (lane == 0) v[row] = s;
  }
}

// M = Wa*Wb^T 3-term split; write M^T split. grid 64.
__global__ __launch_bounds__(256) void k_gemm_mt(const unsigned short* __restrict__ Wa2,
                                                 const unsigned short* __restrict__ Wb2,
                                                 unsigned short* __restrict__ MT2){
  __shared__ __align__(16) unsigned short lsA[8192], lsB[8192];
  const int bm = blockIdx.x >> 3, bn = blockIdx.x & 7;
  f32x4 acc[4][4];
  gemm_core<1, 2>(Wa2 + (size_t)bm * 128 * 2048, 2048,
                  Wb2 + (size_t)bn * 128 * 2048, 2048, 3072, lsA, lsB, acc);
  const int tid = threadIdx.x, lane = tid & 63, w = tid >> 6;
  const int wr = (w >> 1) * 64, wc = (w & 1) * 64, l15 = lane & 15, lg = lane >> 4;
#pragma unroll
  for (int m = 0; m < 4; m++)
#pragma unroll
    for (int n = 0; n < 4; n++){
      const int g  = bn * 128 + wc + n * 16 + l15;
      const int f0 = bm * 128 + wr + m * 16 + lg * 4;
      ushort4 h4, l4;
      split2(acc[m][n][0], h4.x, l4.x); split2(acc[m][n][1], h4.y, l4.y);
      split2(acc[m][n][2], h4.z, l4.z); split2(acc[m][n][3], h4.w, l4.w);
      *(ushort4*)(MT2 + (size_t)g * 2048 + f0) = h4;
      *(ushort4*)(MT2 + (size_t)g * 2048 + 1024 + f0) = l4;
    }
}

// out per frame via featsT: grid 2048.
__global__ __launch_bounds__(256) void k_gemm_out(const unsigned short* __restrict__ FT,
                                                  const unsigned short* __restrict__ Wt,
                                                  float* __restrict__ outp){
  __shared__ __align__(16) unsigned short lsA[8192], lsB[8192];
  const int t = blockIdx.x >> 3, fb = blockIdx.x & 7;
  f32x4 acc[4][4];
  gemm_core<0, 0>(FT + (size_t)fb * 128 * 32768 + (size_t)t * 128, 32768,
                  Wt + (size_t)t * 16384, 128, 128, lsA, lsB, acc);
  const int tid = threadIdx.x, lane = tid & 63, w = tid >> 6;
  const int wr = (w >> 1) * 64, wc = (w & 1) * 64, l15 = lane & 15, lg = lane >> 4;
#pragma unroll
  for (int m = 0; m < 4; m++)
#pragma unroll
    for (int n = 0; n < 4; n++){
      const int s  = wc + n * 16 + l15;
      const int f0 = fb * 128 + wr + m * 16 + lg * 4;
      *(f32x4*)(outp + ((size_t)t * 128 + s) * 1024 + f0) = acc[m][n];
    }
}

// ---------- launcher ----------
extern "C" void kernel_launch(void* const* d_in, const int* in_sizes, int n_in,
                              void* d_out, int out_size, void* d_ws, size_t ws_size,
                              hipStream_t stream) {
  const float* x  = (const float*)d_in[0];
  const float* Wa = (const float*)d_in[2];
  const float* ba = (const float*)d_in[3];
  const float* Wb = (const float*)d_in[4];
  const float* Wg = (const float*)d_in[6];
  const float* bg = (const float*)d_in[7];

  unsigned short* x2  = (unsigned short*)d_ws;            // 32768 x 2048
  unsigned short* Wa2 = x2 + (size_t)32768 * 2048;        // 1024 x 2048
  unsigned short* Wb2 = Wa2 + (size_t)1024 * 2048;        // 1024 x 2048
  unsigned short* WgT = Wb2 + (size_t)1024 * 2048;        // 1024 x 2048
  unsigned short* MT2 = WgT + (size_t)1024 * 2048;        // 1024 x 2048
  unsigned short* FT  = MT2 + (size_t)1024 * 2048;        // 1024 x 32768
  float* scores = (float*)(FT + (size_t)1024 * 32768);    // (spare)
  unsigned short* wts = (unsigned short*)(scores + (size_t)256 * 128 * 128);
  float* wv = (float*)(wts + (size_t)256 * 128 * 128);    // 1024
  float* v  = wv + 1024;                                  // 32768
  size_t need = (size_t)((char*)(v + 32768) - (char*)d_ws);
  if (ws_size < need) return;

  unsigned short* y2 = (unsigned short*)d_out;            // y hi/lo in d_out until PV

  k_split   <<<1024, 256, 0, stream>>>(Wa, Wa2);
  k_split   <<<1024, 256, 0, stream>>>(Wb, Wb2);
  k_splitT  <<<1024, 256, 0, stream>>>(Wg, WgT);
  k_wv      <<<256,  256, 0, stream>>>(Wb, ba, wv);
  k_split_x <<<2048, 256, 0, stream>>>(x, x2, wv, v);
  k_gemm_mt <<<64,   256, 0, stream>>>(Wa2, Wb2, MT2);
  k_gemm256<0, 0, 16, 1><<<512, 512, 0, stream>>>(x2, WgT, FT, bg);      // featsT
  k_gemm256<1, 2, 48, 0><<<512, 512, 0, stream>>>(x2, MT2, y2, nullptr); // y = x*M
  k_scores2 <<<128,  512, 0, stream>>>(y2, x2, v, wts);
  k_gemm_out<<<2048, 256, 0, stream>>>(FT, wts, (float*)d_out);
}

// Round 5
// 517.005 us; speedup vs baseline: 1.1310x; 1.1310x over previous
//
#include <hip/hip_runtime.h>

typedef __attribute__((ext_vector_type(8))) short bf16x8;
typedef __attribute__((ext_vector_type(4))) float f32x4;

// ---------- helpers ----------
__device__ __forceinline__ unsigned short bf16_rne(float x){
  unsigned int u = __float_as_uint(x);
  unsigned int r = (u + 0x7FFFu + ((u >> 16) & 1u)) >> 16;
  return (unsigned short)r;
}
__device__ __forceinline__ float bf16_tof(unsigned short h){
  return __uint_as_float(((unsigned int)h) << 16);
}
__device__ __forceinline__ void split2(float x, unsigned short &hi, unsigned short &lo){
  hi = bf16_rne(x);
  lo = bf16_rne(x - bf16_tof(hi));
}
__device__ __forceinline__ void gload_lds16(const void* g, void* l){
  __builtin_amdgcn_global_load_lds((const __attribute__((address_space(1))) void*)g,
                                   (__attribute__((address_space(3))) void*)l, 16, 0, 0);
}
#define VM(N)  asm volatile("s_waitcnt vmcnt(" #N ")" ::: "memory")
#define LGKM0()  do { asm volatile("s_waitcnt lgkmcnt(0)" ::: "memory"); \
                      __builtin_amdgcn_sched_barrier(0); } while(0)
#define BAR()  do { __builtin_amdgcn_s_barrier(); \
                    __builtin_amdgcn_sched_barrier(0); } while(0)

// K-index remap for the 3-term split expressed as a K=3072 concat GEMM.
// MAP 0: identity. MAP 1: blocks [hi|lo|hi]. MAP 2: blocks [hi|hi|lo].
template<int MAP>
__device__ __forceinline__ int kmap(int k){
  if (MAP == 1) return (k < 2048) ? k : (k - 2048);
  if (MAP == 2) return (k < 1024) ? k : (k - 1024);
  return k;
}

// ============================================================================
// 256x256 GEMM, BK=64, 512 threads (8 waves 2x4), 2 LDS slots x 64KB.
// 2 barriers per K-tile. Gate ledger (FIFO, per wave; stage quarters
// q0=A.k0,q1=B.k0,q2=B.k1,q3=A.k1, 2 gloads each, issued in phases P0..P3):
//   gate1(t): VM(4)  -> q0,q1(t) landed (q2,q3(t) still allowed in flight)
//   gate2(t): VM(4)  -> q2,q3(t) landed (q0,q1(t+1) allowed)   [tail: VM(0)]
// Each wave's VM precedes the barrier => all waves' loads landed at cross.
// XOR-swizzled LDS (R2-verified: 0 bank conflicts).
// EPI 0: split hi/lo write (y). EPI 1: bf16(acc+bias[col])^T write (featsT).
// ============================================================================
template<int MAPA, int MAPB, int NK, int EPI>
__global__ __launch_bounds__(512, 2) void k_gemm256(
    const unsigned short* __restrict__ A, const unsigned short* __restrict__ B,
    unsigned short* __restrict__ outp, const float* __restrict__ bias)
{
  __shared__ __align__(16) unsigned short lds_u[65536];   // 128 KiB
  char* ldsb = (char*)lds_u;

  int bid = blockIdx.x;                 // XCD-aware swizzle (grid 512 % 8 == 0)
  bid = (bid & 7) * 64 + (bid >> 3);
  const int bm = bid >> 2, bn = bid & 3;

  const int tid  = threadIdx.x;
  const int w    = tid >> 6;
  const int lane = tid & 63;
  const int wm   = w >> 2;              // 0..1
  const int wn   = w & 3;               // 0..3
  const int l15  = lane & 15;
  const int lg   = lane >> 4;

  // staging source map (inverse swizzle), 2 chunks per 16K region
  int srow[2], slg[2];
#pragma unroll
  for (int j = 0; j < 2; j++){
    int o16 = j * 512 + tid;
    int p = o16 >> 3, s = o16 & 7;
    int q = s ^ (p & 7);
    srow[j] = 2 * p + (q >> 2);
    slg[j]  = q & 3;
  }
  const unsigned short* aS0 = A + (size_t)(bm * 256 + srow[0]) * 2048 + slg[0] * 8;
  const unsigned short* aS1 = A + (size_t)(bm * 256 + srow[1]) * 2048 + slg[1] * 8;
  const unsigned short* bS0 = B + (size_t)(bn * 256 + srow[0]) * 2048 + slg[0] * 8;
  const unsigned short* bS1 = B + (size_t)(bn * 256 + srow[1]) * 2048 + slg[1] * 8;

  const int sA   = (((l15 & 1) << 2) | lg) ^ ((l15 >> 1) & 7);
  const int rps  = (l15 >> 1) * 128 + sA * 16;

  f32x4 acc[8][4];
  f32x4 zero = {0.f, 0.f, 0.f, 0.f};
#pragma unroll
  for (int m = 0; m < 8; m++)
#pragma unroll
    for (int n = 0; n < 4; n++) acc[m][n] = zero;

  auto STAGE_Q = [&](int t, int q){
    char* slot = ldsb + (size_t)(t & 1) * 65536;
    const int kbA = kmap<MAPA>(t * 64);
    const int kbB = kmap<MAPB>(t * 64);
    if (q == 0){
      gload_lds16(aS0 + kbA,      slot +         w * 1024);
      gload_lds16(aS1 + kbA,      slot +  8192 + w * 1024);
    } else if (q == 1){
      gload_lds16(bS0 + kbB,      slot + 32768 + w * 1024);
      gload_lds16(bS1 + kbB,      slot + 40960 + w * 1024);
    } else if (q == 2){
      gload_lds16(bS0 + kbB + 32, slot + 49152 + w * 1024);
      gload_lds16(bS1 + kbB + 32, slot + 57344 + w * 1024);
    } else {
      gload_lds16(aS0 + kbA + 32, slot + 16384 + w * 1024);
      gload_lds16(aS1 + kbA + 32, slot + 24576 + w * 1024);
    }
  };

  STAGE_Q(0, 0); STAGE_Q(0, 1); STAGE_Q(0, 2); STAGE_Q(0, 3);

#pragma unroll 1
  for (int t = 0; t < NK; t++){
    const char* sb = ldsb + (size_t)(t & 1) * 65536;
    const bool pre = (t + 1 < NK);
    bf16x8 aF[4], bF[4], aG[4], bF2[4], aF2[4], aG2[4];

    VM(4);                              // gate1: q0,q1(t)
    BAR();
    // P0
    if (pre) STAGE_Q(t + 1, 0);
#pragma unroll
    for (int m = 0; m < 4; m++) aF[m] = *(const bf16x8*)(sb + wm * 8192 + m * 1024 + rps);
#pragma unroll
    for (int n = 0; n < 4; n++) bF[n] = *(const bf16x8*)(sb + 32768 + wn * 4096 + n * 1024 + rps);
    LGKM0();
    __builtin_amdgcn_s_setprio(1);
#pragma unroll
    for (int m = 0; m < 4; m++)
#pragma unroll
      for (int n = 0; n < 4; n++)
        acc[m][n] = __builtin_amdgcn_mfma_f32_16x16x32_bf16(aF[m], bF[n], acc[m][n], 0, 0, 0);
    __builtin_amdgcn_s_setprio(0);
    // P1
    if (pre) STAGE_Q(t + 1, 1);
#pragma unroll
    for (int m = 0; m < 4; m++) aG[m] = *(const bf16x8*)(sb + wm * 8192 + (m + 4) * 1024 + rps);
    LGKM0();
    __builtin_amdgcn_s_setprio(1);
#pragma unroll
    for (int m = 0; m < 4; m++)
#pragma unroll
      for (int n = 0; n < 4; n++)
        acc[m + 4][n] = __builtin_amdgcn_mfma_f32_16x16x32_bf16(aG[m], bF[n], acc[m + 4][n], 0, 0, 0);
    __builtin_amdgcn_s_setprio(0);

    if (pre) { VM(4); } else { VM(0); } // gate2: q2,q3(t)
    BAR();
    // P2
    if (pre) STAGE_Q(t + 1, 2);
#pragma unroll
    for (int m = 0; m < 4; m++) aF2[m] = *(const bf16x8*)(sb + 16384 + wm * 8192 + m * 1024 + rps);
#pragma unroll
    for (int n = 0; n < 4; n++) bF2[n] = *(const bf16x8*)(sb + 49152 + wn * 4096 + n * 1024 + rps);
    LGKM0();
    __builtin_amdgcn_s_setprio(1);
#pragma unroll
    for (int m = 0; m < 4; m++)
#pragma unroll
      for (int n = 0; n < 4; n++)
        acc[m][n] = __builtin_amdgcn_mfma_f32_16x16x32_bf16(aF2[m], bF2[n], acc[m][n], 0, 0, 0);
    __builtin_amdgcn_s_setprio(0);
    // P3
    if (pre) STAGE_Q(t + 1, 3);
#pragma unroll
    for (int m = 0; m < 4; m++) aG2[m] = *(const bf16x8*)(sb + 16384 + wm * 8192 + (m + 4) * 1024 + rps);
    LGKM0();
    __builtin_amdgcn_s_setprio(1);
#pragma unroll
    for (int m = 0; m < 4; m++)
#pragma unroll
      for (int n = 0; n < 4; n++)
        acc[m + 4][n] = __builtin_amdgcn_mfma_f32_16x16x32_bf16(aG2[m], bF2[n], acc[m + 4][n], 0, 0, 0);
    __builtin_amdgcn_s_setprio(0);
  }

#pragma unroll
  for (int m = 0; m < 8; m++)
#pragma unroll
    for (int n = 0; n < 4; n++){
      const int col  = bn * 256 + wn * 64 + n * 16 + l15;
      const int row0 = bm * 256 + wm * 128 + m * 16 + lg * 4;
      if (EPI == 0){
#pragma unroll
        for (int q = 0; q < 4; q++){
          unsigned short hi, lo; split2(acc[m][n][q], hi, lo);
          const size_t base = (size_t)(row0 + q) * 2048;
          outp[base + col] = hi;
          outp[base + 1024 + col] = lo;
        }
      } else {
        const float bgv = bias[col];
        ushort4 h4;
        h4.x = bf16_rne(acc[m][n][0] + bgv); h4.y = bf16_rne(acc[m][n][1] + bgv);
        h4.z = bf16_rne(acc[m][n][2] + bgv); h4.w = bf16_rne(acc[m][n][3] + bgv);
        *(ushort4*)(outp + (size_t)col * 32768 + row0) = h4;
      }
    }
}

// ============================================================================
// Fused per-frame kernel: scores (K=3072) -> softmax -> PV (out = P @ feats).
// 256 blocks (1 frame each) x 256 threads (4 waves, 2x2, wave-tile 64x64).
// LDS: scores 2 slots x 32KB at [0,64K) (regions Y.k0|Y.k1|X.k0|X.k1, 8KB,
// R2 xor swizzle); softmax fp32 at [0,64K); P bf16 (chunk-xor) [64K,96K);
// F dbuf 2x16KB [96K,128K). out rows of this frame alias this block's own
// y2 rows in d_out (read fully before overwrite; block-local).
// ============================================================================
__global__ __launch_bounds__(256, 1) void k_frame(
    const unsigned short* Y2, const unsigned short* X2,
    const float* __restrict__ v, const unsigned short* __restrict__ FT,
    float* outp)
{
  __shared__ __align__(16) unsigned short lds_u[65536];   // 128 KiB
  char* ldsb = (char*)lds_u;

  const int frame = blockIdx.x;
  const int tid  = threadIdx.x;
  const int w    = tid >> 6;
  const int lane = tid & 63;
  const int wm   = w >> 1, wn = w & 1;
  const int l15  = lane & 15;
  const int lg   = lane >> 4;

  // staging chunk map for 8KB regions (128 rows x 32 k): o = tid + 256*j
  int srow[2], slg[2];
#pragma unroll
  for (int j = 0; j < 2; j++){
    int o = j * 256 + tid;
    int p = o >> 3, s = o & 7;
    int q = s ^ (p & 7);
    srow[j] = 2 * p + (q >> 2);
    slg[j]  = q & 3;
  }
  const unsigned short* yS0 = Y2 + (size_t)(frame * 128 + srow[0]) * 2048 + slg[0] * 8;
  const unsigned short* yS1 = Y2 + (size_t)(frame * 128 + srow[1]) * 2048 + slg[1] * 8;
  const unsigned short* xS0 = X2 + (size_t)(frame * 128 + srow[0]) * 2048 + slg[0] * 8;
  const unsigned short* xS1 = X2 + (size_t)(frame * 128 + srow[1]) * 2048 + slg[1] * 8;

  const int sA  = (((l15 & 1) << 2) | lg) ^ ((l15 >> 1) & 7);
  const int rps = (l15 >> 1) * 128 + sA * 16;

  f32x4 acc[4][4];
  f32x4 zero = {0.f, 0.f, 0.f, 0.f};
#pragma unroll
  for (int m = 0; m < 4; m++)
#pragma unroll
    for (int n = 0; n < 4; n++) acc[m][n] = zero;

  // stage one k-half (ks) of tile t: Y.ks + X.ks (4 gloads)
  auto STAGE_K = [&](int t, int ks){
    char* slot = ldsb + (size_t)(t & 1) * 32768;
    const int kY = kmap<2>(t * 64) + ks * 32;
    const int kX = kmap<1>(t * 64) + ks * 32;
    gload_lds16(yS0 + kY, slot + ks * 8192 +        tid * 16 - (tid & 255) * 0 + (0) * 4096 + (tid >> 8) * 4096);
    gload_lds16(yS1 + kY, slot + ks * 8192 + 4096 + tid * 16);
    gload_lds16(xS0 + kX, slot + 16384 + ks * 8192 +        tid * 16);
    gload_lds16(xS1 + kX, slot + 16384 + ks * 8192 + 4096 + tid * 16);
  };
  // NOTE: first gload dst simplifies to slot + ks*8192 + tid*16 (j=0 chunk)
  // (the expression above is written defensively; tid>>8 == 0 for 256 thr)

  const int NK = 48;
  STAGE_K(0, 0); STAGE_K(0, 1);

#pragma unroll 1
  for (int t = 0; t < NK; t++){
    const char* sb = ldsb + (size_t)(t & 1) * 32768;
    const bool pre = (t + 1 < NK);
    bf16x8 aF[4], bF[4], aF2[4], bF2[4];

    VM(4);                      // gate1: k0(t) landed (k1(t) allowed)
    BAR();
    if (pre) STAGE_K(t + 1, 0);
#pragma unroll
    for (int m = 0; m < 4; m++) aF[m] = *(const bf16x8*)(sb + wm * 4096 + m * 1024 + rps);
#pragma unroll
    for (int n = 0; n < 4; n++) bF[n] = *(const bf16x8*)(sb + 16384 + wn * 4096 + n * 1024 + rps);
    LGKM0();
    __builtin_amdgcn_s_setprio(1);
#pragma unroll
    for (int m = 0; m < 4; m++)
#pragma unroll
      for (int n = 0; n < 4; n++)
        acc[m][n] = __builtin_amdgcn_mfma_f32_16x16x32_bf16(aF[m], bF[n], acc[m][n], 0, 0, 0);
    __builtin_amdgcn_s_setprio(0);

    if (pre) { VM(4); } else { VM(0); } // gate2: k1(t) landed
    BAR();
    if (pre) STAGE_K(t + 1, 1);
#pragma unroll
    for (int m = 0; m < 4; m++) aF2[m] = *(const bf16x8*)(sb + 8192 + wm * 4096 + m * 1024 + rps);
#pragma unroll
    for (int n = 0; n < 4; n++) bF2[n] = *(const bf16x8*)(sb + 24576 + wn * 4096 + n * 1024 + rps);
    LGKM0();
    __builtin_amdgcn_s_setprio(1);
#pragma unroll
    for (int m = 0; m < 4; m++)
#pragma unroll
      for (int n = 0; n < 4; n++)
        acc[m][n] = __builtin_amdgcn_mfma_f32_16x16x32_bf16(aF2[m], bF2[n], acc[m][n], 0, 0, 0);
    __builtin_amdgcn_s_setprio(0);
  }

  // ---- softmax: acc -> LDS fp32 (rotation swizzle), reduce, P bf16 to LDS ----
  BAR();
  float* sf = (float*)ldsb;                        // 128 x 128 fp32 = 64 KB
#pragma unroll
  for (int m = 0; m < 4; m++)
#pragma unroll
    for (int n = 0; n < 4; n++){
      const int col = wn * 64 + n * 16 + l15;
#pragma unroll
      for (int q = 0; q < 4; q++){
        const int row = wm * 64 + m * 16 + lg * 4 + q;
        sf[row * 128 + ((col + (row & 31) * 4) & 127)] = acc[m][n][q];
      }
    }
  LGKM0(); BAR();
  unsigned short* Pb = (unsigned short*)(ldsb + 65536);  // P: row*256B, chunk-xor
  {
    const float* vr = v + (size_t)frame * 128;
#pragma unroll 1
    for (int i = 0; i < 32; i++){
      const int row = w * 32 + i;
      const float* rp = sf + row * 128;
      const int rot = (row & 31) * 4;
      float a = rp[(lane + rot) & 127]      + vr[lane];
      float b = rp[(lane + 64 + rot) & 127] + vr[lane + 64];
      float mx = fmaxf(a, b);
      for (int o = 32; o; o >>= 1) mx = fmaxf(mx, __shfl_xor(mx, o));
      float ea = __expf(a - mx), eb = __expf(b - mx);
      float s = ea + eb;
      for (int o = 32; o; o >>= 1) s += __shfl_xor(s, o);
      const float inv = 1.0f / s;
      unsigned short* prow = (unsigned short*)((char*)Pb + row * 256);
      const int j0 = lane, j1 = lane + 64;
      *(unsigned short*)((char*)prow + (((j0 >> 3) ^ (row & 15)) * 16) + (j0 & 7) * 2) = bf16_rne(ea * inv);
      *(unsigned short*)((char*)prow + (((j1 >> 3) ^ (row & 15)) * 16) + (j1 & 7) * 2) = bf16_rne(eb * inv);
    }
  }
  LGKM0(); BAR();

  // ---- PV: out[s][f] = sum_j P[s][j] * FT[f][frame*128+j], 16 f-halves ----
  char* Fb = ldsb + 98304;                         // 2 x 16KB slots
  auto STAGE_F = [&](int h){
    char* slot = Fb + (size_t)(h & 1) * 16384;
#pragma unroll
    for (int j = 0; j < 4; j++){
      const int o = j * 256 + tid;
      const int a = o >> 4, c = o & 15;
      gload_lds16(FT + (size_t)(h * 64 + a) * 32768 + frame * 128 + (c ^ (a & 15)) * 8,
                  slot + (size_t)o * 16);
    }
  };
  STAGE_F(0);

#pragma unroll 1
  for (int h = 0; h < 16; h++){
    VM(0);                       // drain F(h) (+prior stores); F(h+1) not yet issued
    BAR();
    if (h + 1 < 16) STAGE_F(h + 1);
    const char* fs = Fb + (size_t)(h & 1) * 16384;
    bf16x8 pF[4][4], fF[4][2];
#pragma unroll
    for (int ks = 0; ks < 4; ks++){
#pragma unroll
      for (int m = 0; m < 4; m++){
        const int row = wm * 64 + m * 16 + l15;
        pF[ks][m] = *(const bf16x8*)((char*)Pb + row * 256 + (((ks * 4 + lg) ^ (row & 15)) * 16));
      }
#pragma unroll
      for (int n = 0; n < 2; n++){
        const int al = wn * 32 + n * 16 + l15;
        fF[ks][n] = *(const bf16x8*)(fs + al * 256 + (((ks * 4 + lg) ^ (al & 15)) * 16));
      }
    }
    LGKM0();
    f32x4 accP[4][2];
#pragma unroll
    for (int m = 0; m < 4; m++)
#pragma unroll
      for (int n = 0; n < 2; n++) accP[m][n] = zero;
    __builtin_amdgcn_s_setprio(1);
#pragma unroll
    for (int ks = 0; ks < 4; ks++)
#pragma unroll
      for (int m = 0; m < 4; m++)
#pragma unroll
        for (int n = 0; n < 2; n++)
          accP[m][n] = __builtin_amdgcn_mfma_f32_16x16x32_bf16(pF[ks][m], fF[ks][n], accP[m][n], 0, 0, 0);
    __builtin_amdgcn_s_setprio(0);
#pragma unroll
    for (int m = 0; m < 4; m++)
#pragma unroll
      for (int n = 0; n < 2; n++){
        const int f = h * 64 + wn * 32 + n * 16 + l15;
        const int r0 = wm * 64 + m * 16 + lg * 4;
#pragma unroll
        for (int q = 0; q < 4; q++)
          outp[((size_t)frame * 128 + r0 + q) * 1024 + f] = accP[m][n][q];
      }
  }
}

// ============================================================================
// m97-style core for the small M=N=1024 GEMM (mt).
// ============================================================================
template<int MAPA, int MAPB>
__device__ __forceinline__ void gemm_core(const unsigned short* __restrict__ A, int lda,
                                          const unsigned short* __restrict__ B, int ldb,
                                          int Kv,
                                          unsigned short* lsA, unsigned short* lsB,
                                          f32x4 acc[4][4])
{
  const int tid  = threadIdx.x;
  const int lane = tid & 63;
  const int w    = tid >> 6;
  const int wr   = (w >> 1) * 64;
  const int wc   = (w & 1) * 64;
  const int l15  = lane & 15;
  const int lg   = lane >> 4;

  f32x4 zero = {0.f, 0.f, 0.f, 0.f};
#pragma unroll
  for (int m = 0; m < 4; m++)
#pragma unroll
    for (int n = 0; n < 4; n++)
      acc[m][n] = zero;

  const int srow = tid >> 3;
  const int skk  = (tid & 7) << 3;

  for (int kt = 0; kt < Kv; kt += 64){
    const int ka = kmap<MAPA>(kt) + skk;
    const int kb = kmap<MAPB>(kt) + skk;
    __syncthreads();
#pragma unroll
    for (int i = 0; i < 4; i++){
      const int row = i * 32 + srow;
      gload_lds16(A + (size_t)row * lda + ka, lsA + i * 2048 + w * 512);
      gload_lds16(B + (size_t)row * ldb + kb, lsB + i * 2048 + w * 512);
    }
    __syncthreads();
#pragma unroll
    for (int s2 = 0; s2 < 2; s2++){
      bf16x8 af[4], bfr[4];
#pragma unroll
      for (int m = 0; m < 4; m++)
        af[m] = *(const bf16x8*)(lsA + (wr + m * 16 + l15) * 64 + s2 * 32 + lg * 8);
#pragma unroll
      for (int n = 0; n < 4; n++)
        bfr[n] = *(const bf16x8*)(lsB + (wc + n * 16 + l15) * 64 + s2 * 32 + lg * 8);
#pragma unroll
      for (int m = 0; m < 4; m++)
#pragma unroll
        for (int n = 0; n < 4; n++)
          acc[m][n] = __builtin_amdgcn_mfma_f32_16x16x32_bf16(af[m], bfr[n], acc[m][n], 0, 0, 0);
    }
  }
}

// ---------- small prep kernels ----------
__global__ __launch_bounds__(256) void k_split(const float* __restrict__ src,
                                               unsigned short* __restrict__ dst){
  const int row = blockIdx.x;
  const int c = threadIdx.x * 4;
  float4 val = *(const float4*)(src + (size_t)row * 1024 + c);
  ushort4 h, l;
  split2(val.x, h.x, l.x); split2(val.y, h.y, l.y);
  split2(val.z, h.z, l.z); split2(val.w, h.w, l.w);
  *(ushort4*)(dst + (size_t)row * 2048 + c) = h;
  *(ushort4*)(dst + (size_t)row * 2048 + 1024 + c) = l;
}

__global__ __launch_bounds__(256) void k_splitT(const float* __restrict__ src,
                                                unsigned short* __restrict__ dstT){
  const int row = blockIdx.x;
  const int c0 = threadIdx.x * 4;
  float4 val = *(const float4*)(src + (size_t)row * 1024 + c0);
  float vv[4] = {val.x, val.y, val.z, val.w};
#pragma unroll
  for (int i = 0; i < 4; i++){
    unsigned short h, l; split2(vv[i], h, l);
    dstT[(size_t)(c0 + i) * 2048 + row] = h;
    dstT[(size_t)(c0 + i) * 2048 + 1024 + row] = l;
  }
}

__global__ __launch_bounds__(256) void k_wv(const float* __restrict__ Wb,
                                            const float* __restrict__ ba,
                                            float* __restrict__ wv){
  const int row = blockIdx.x * 4 + (threadIdx.x >> 6);
  const int lane = threadIdx.x & 63;
  float s = 0.f;
#pragma unroll
  for (int j = 0; j < 4; j++){
    const int c = lane * 4 + j * 256;
    float4 wb = *(const float4*)(Wb + (size_t)row * 1024 + c);
    float4 bb = *(const float4*)(ba + c);
    s += wb.x * bb.x + wb.y * bb.y + wb.z * bb.z + wb.w * bb.w;
  }
  for (int o = 32; o; o >>= 1) s += __shfl_xor(s, o);
  if (lane == 0) wv[row] = s;
}

__global__ __launch_bounds__(256) void k_split_x(const float* __restrict__ x,
                                                 unsigned short* __restrict__ x2,
                                                 const float* __restrict__ wv,
                                                 float* __restrict__ v){
  const int w = threadIdx.x >> 6, lane = threadIdx.x & 63;
#pragma unroll
  for (int it = 0; it < 4; it++){
    const int row = blockIdx.x * 4 + w + it * 8192;
    float s = 0.f;
#pragma unroll
    for (int j = 0; j < 4; j++){
      const int c = lane * 4 + j * 256;
      float4 val = *(const float4*)(x + (size_t)row * 1024 + c);
      float4 wvv = *(const float4*)(wv + c);
      ushort4 h, l;
      split2(val.x, h.x, l.x); split2(val.y, h.y, l.y);
      split2(val.z, h.z, l.z); split2(val.w, h.w, l.w);
      *(ushort4*)(x2 + (size_t)row * 2048 + c) = h;
      *(ushort4*)(x2 + (size_t)row * 2048 + 1024 + c) = l;
      s += val.x * wvv.x + val.y * wvv.y + val.z * wvv.z + val.w * wvv.w;
    }
    for (int o = 32; o; o >>= 1) s += __shfl_xor(s, o);
    if (lane == 0) v[row] = s;
  }
}

// M = Wa*Wb^T 3-term split; write M^T split. grid 64.
__global__ __launch_bounds__(256) void k_gemm_mt(const unsigned short* __restrict__ Wa2,
                                                 const unsigned short* __restrict__ Wb2,
                                                 unsigned short* __restrict__ MT2){
  __shared__ __align__(16) unsigned short lsA[8192], lsB[8192];
  const int bm = blockIdx.x >> 3, bn = blockIdx.x & 7;
  f32x4 acc[4][4];
  gemm_core<1, 2>(Wa2 + (size_t)bm * 128 * 2048, 2048,
                  Wb2 + (size_t)bn * 128 * 2048, 2048, 3072, lsA, lsB, acc);
  const int tid = threadIdx.x, lane = tid & 63, w = tid >> 6;
  const int wr = (w >> 1) * 64, wc = (w & 1) * 64, l15 = lane & 15, lg = lane >> 4;
#pragma unroll
  for (int m = 0; m < 4; m++)
#pragma unroll
    for (int n = 0; n < 4; n++){
      const int g  = bn * 128 + wc + n * 16 + l15;
      const int f0 = bm * 128 + wr + m * 16 + lg * 4;
      ushort4 h4, l4;
      split2(acc[m][n][0], h4.x, l4.x); split2(acc[m][n][1], h4.y, l4.y);
      split2(acc[m][n][2], h4.z, l4.z); split2(acc[m][n][3], h4.w, l4.w);
      *(ushort4*)(MT2 + (size_t)g * 2048 + f0) = h4;
      *(ushort4*)(MT2 + (size_t)g * 2048 + 1024 + f0) = l4;
    }
}

// ---------- launcher ----------
extern "C" void kernel_launch(void* const* d_in, const int* in_sizes, int n_in,
                              void* d_out, int out_size, void* d_ws, size_t ws_size,
                              hipStream_t stream) {
  const float* x  = (const float*)d_in[0];
  const float* Wa = (const float*)d_in[2];
  const float* ba = (const float*)d_in[3];
  const float* Wb = (const float*)d_in[4];
  const float* Wg = (const float*)d_in[6];
  const float* bg = (const float*)d_in[7];

  unsigned short* x2  = (unsigned short*)d_ws;            // 32768 x 2048
  unsigned short* Wa2 = x2 + (size_t)32768 * 2048;        // 1024 x 2048
  unsigned short* Wb2 = Wa2 + (size_t)1024 * 2048;        // 1024 x 2048
  unsigned short* WgT = Wb2 + (size_t)1024 * 2048;        // 1024 x 2048
  unsigned short* MT2 = WgT + (size_t)1024 * 2048;        // 1024 x 2048
  unsigned short* FT  = MT2 + (size_t)1024 * 2048;        // 1024 x 32768 (feats^T bf16)
  float* wv = (float*)(FT + (size_t)1024 * 32768);        // 1024
  float* v  = wv + 1024;                                  // 32768
  size_t need = (size_t)((char*)(v + 32768) - (char*)d_ws);
  if (ws_size < need) return;

  unsigned short* y2 = (unsigned short*)d_out;            // y hi/lo in d_out until PV

  k_split   <<<1024, 256, 0, stream>>>(Wa, Wa2);
  k_split   <<<1024, 256, 0, stream>>>(Wb, Wb2);
  k_splitT  <<<1024, 256, 0, stream>>>(Wg, WgT);
  k_wv      <<<256,  256, 0, stream>>>(Wb, ba, wv);
  k_split_x <<<2048, 256, 0, stream>>>(x, x2, wv, v);
  k_gemm_mt <<<64,   256, 0, stream>>>(Wa2, Wb2, MT2);
  k_gemm256<0, 0, 16, 1><<<512, 512, 0, stream>>>(x2, WgT, FT, bg);      // featsT
  k_gemm256<1, 2, 48, 0><<<512, 512, 0, stream>>>(x2, MT2, y2, nullptr); // y = x*M
  k_frame   <<<256,  256, 0, stream>>>(y2, x2, v, FT, (float*)d_out);    // scores+softmax+PV
}